// Round 8
// baseline (161.098 us; speedup 1.0000x reference)
//
#include <hip/hip_runtime.h>
#include <stdint.h>

// Problem constants (HierarchicalAWX): B=16384, D=1024, UNITS=1500, C=2000
// Structural fact: R_t[0:1500] == eye(1500) => leaf outputs are elementwise
// clip(sigmoid, 1e-3, sqrt(1-1e-6)) from GEMM1's epilogue; only the 500
// internal classes need the second GEMM.
#define BROWS 16384
#define DDIM 1024
#define UNITSN 1500
#define UNITSP 1536   // padded K2 / N1
#define CCLS 2000
#define NINT 500      // internal classes
#define NINTP 512     // padded
#define EPSV 1e-6f
#define LEAF_LO 1e-3f        // sqrt(EPSV)
#define LEAF_HI 0.9999995f   // sqrt(1-EPSV)

typedef __bf16 bf16x8 __attribute__((ext_vector_type(8)));
typedef float f32x4 __attribute__((ext_vector_type(4)));
typedef unsigned short u16x4v __attribute__((ext_vector_type(4)));

__device__ __forceinline__ unsigned short f2bf(float f) {
  union { float f; uint32_t u; } x; x.f = f;
  uint32_t r = x.u + 0x7fffu + ((x.u >> 16) & 1u);
  return (unsigned short)(r >> 16);
}

__device__ __forceinline__ float fast_rcp(float x) {
  float r; asm("v_rcp_f32 %0, %1" : "=v"(r) : "v"(x)); return r;
}
__device__ __forceinline__ float fast_sqrt(float x) {
  float r; asm("v_sqrt_f32 %0, %1" : "=v"(r) : "v"(x)); return r;
}

// async global -> LDS, 16B per lane. LDS dest is wave-uniform base; HW adds lane*16.
__device__ __forceinline__ void gload_lds16(const void* g, void* l) {
  __builtin_amdgcn_global_load_lds(
      reinterpret_cast<const __attribute__((address_space(1))) void*>(
          reinterpret_cast<uintptr_t>(g)),
      reinterpret_cast<__attribute__((address_space(3))) void*>(
          (uint32_t)reinterpret_cast<uintptr_t>(l)),
      16, 0, 0);
}

#define VMW(n) asm volatile("s_waitcnt vmcnt(" #n ")" ::: "memory")
#define LGKM0() asm volatile("s_waitcnt lgkmcnt(0)" ::: "memory")
#define SBAR() __builtin_amdgcn_s_barrier()
#define SCHED0() __builtin_amdgcn_sched_barrier(0)
#define MFMA __builtin_amdgcn_mfma_f32_16x16x32_bf16

// ---- merged prep kernel -----------------------------------------------------
__global__ __launch_bounds__(256) void k_prep(
    const float* __restrict__ inputs, const float* __restrict__ lin,
    const float* __restrict__ R, unsigned short* __restrict__ Ab,
    unsigned short* __restrict__ wt, unsigned short* __restrict__ Rb) {
  const int b = blockIdx.x, t = threadIdx.x;

  // --- W^T: lin (D x UNITS f32) -> wt (UNITSP x D bf16), zero-pad rows
  if (b < 1536) {
    __shared__ float tle[32][33];
    const int nb = (b % 48) * 32;  // over UNITSP
    const int kb = (b / 48) * 32;  // over D
    const int tx = t & 31, ty = t >> 5;
#pragma unroll
    for (int s = 0; s < 32; s += 8) {
      int k = kb + ty + s, n = nb + tx;
      tle[ty + s][tx] = (n < UNITSN) ? lin[k * UNITSN + n] : 0.f;
    }
    __syncthreads();
#pragma unroll
    for (int s = 0; s < 32; s += 8) {
      int n = nb + ty + s, k = kb + tx;
      wt[n * DDIM + k] = f2bf(tle[tx][ty + s]);
    }
  }

  // --- A cvt: 16384x1024 f32 -> bf16
  const int gtid = b * 256 + t;
  const float4* in4 = (const float4*)inputs;
  for (int i = gtid; i < (BROWS * DDIM) / 4; i += 2048 * 256) {
    float4 v = in4[i];
    u16x4v o;
    o.x = f2bf(v.x); o.y = f2bf(v.y); o.z = f2bf(v.z); o.w = f2bf(v.w);
    *reinterpret_cast<u16x4v*>(Ab + i * 4) = o;
  }

  // --- internal R rows: Rb[r][u] = R[1500+r][u], (512 x 1536) zero-padded
  for (int i = gtid; i < NINTP * UNITSP; i += 2048 * 256) {
    int r = i / UNITSP;
    int u = i - r * UNITSP;
    float v = (r < NINT && u < UNITSN) ? R[(size_t)(UNITSN + r) * UNITSN + u] : 0.f;
    Rb[i] = f2bf(v);
  }
}

// ---- GEMM1 v3: 128x128 tile, BK=64, A-only LDS (4 bufs), B global->reg -----
// 8 waves (2M x 4N), per-wave 64x32 = 4x2 frags, 16 MFMA per barrier.
// W^T (3MB) is L2-resident: B frags load straight to regs, double-buffered,
// base-ptr + literal offset (t*128B <= 1920, folds into the 13-bit imm).
// LDS = 4 bufs x (128x64 bf16 = 16KB) = 64KB -> 2 blocks/CU. One barrier per
// K-tile; A staged 3 tiles ahead. Counted vmcnt via younger-than-target
// arithmetic (in-order retirement): steady VMW(12); tail 12,10,8,-.
// lgkmcnt(0) before each barrier => buf recycle race-free (stage into buf p
// issues only after the barrier that follows all reads of p).
__global__ __launch_bounds__(512, 4) void k_gemm1b(
    const unsigned short* __restrict__ A,   // 16384 x 1024 bf16
    const unsigned short* __restrict__ Bt,  // 1536 x 1024 bf16 (W^T)
    const float* __restrict__ bias,
    unsigned short* __restrict__ o2,        // 16384 x 1536 bf16
    float* __restrict__ outf) {             // leaf cols of 16384 x 2000 f32
  constexpr int K = DDIM;   // 1024, 16 K-tiles of 64
  constexpr int NBX = 12;
  __shared__ char smem[65536];  // 4 x 16KB A bufs

  const int nwg = (int)gridDim.x;
  const int qx = nwg >> 3;
  const int bid = (int)blockIdx.x;
  const int wg = (bid & 7) * qx + (bid >> 3);
  const int bx = wg % NBX, by = wg / NBX;
  const int brow = by << 7, bcol = bx << 7;

  const int tid = (int)threadIdx.x;
  const int lane = tid & 63;
  const int w = tid >> 6;
  const int wr = w >> 2, wc = w & 3;  // per-wave 64 rows x 32 cols

  // A staging: 512 threads cover 64 rows x 8 chunks(16B) per unit; 2 units/tile.
  // Source chunk pre-XORed by row&7 so linear LDS lands swizzled (rule #21).
  const int srow = tid >> 3;          // 0..63
  const int skc = tid & 7;            // 0..7
  const unsigned short* gA0 =
      A + (size_t)(brow + srow) * K + ((skc ^ (srow & 7)) << 3);
  const unsigned short* gA1 = gA0 + (size_t)64 * K;
  const int sW = w << 10;  // wave-uniform LDS byte base within a unit

  // A fragment reads: row = wr*64 + i*16 + (lane&15); chunk = (ks*4+(lane>>4)) ^ (lane&7)
  const int aBase = (((wr << 6) + (lane & 15)) << 7) + (((lane >> 4) ^ (lane & 7)) << 4);

  // B fragment pointers (row-major W^T [1536][1024]); per-tile offset = t*64 elems
  const unsigned short* pB0 =
      Bt + (size_t)(bcol + (wc << 5) + (lane & 15)) * K + ((lane >> 4) << 3);
  const unsigned short* pB1 = pB0 + (size_t)16 * K;

#define STG(bs, t) do { \
    gload_lds16(gA0 + (size_t)(t) * 64, smem + (bs) * 16384 + sW); \
    gload_lds16(gA1 + (size_t)(t) * 64, smem + (bs) * 16384 + 8192 + sW); \
  } while (0)
#define LDA1(p, i, ks) (*reinterpret_cast<const bf16x8*>( \
    smem + (p) * 16384 + (aBase ^ ((ks) * 64)) + (i) * 2048))
#define LB(pp, ks, t) (*reinterpret_cast<const bf16x8*>((pp) + (t) * 64 + (ks) * 32))

  f32x4 acc[4][2] = {};
  bf16x8 BX0, BX1, BX2, BX3, BY0, BY1, BY2, BY3;

  // prologue: B(0) -> BX; stage A tiles 0,1,2 -> bufs 0,1,2
  BX0 = LB(pB0, 0, 0); BX1 = LB(pB0, 1, 0); BX2 = LB(pB1, 0, 0); BX3 = LB(pB1, 1, 0);
  STG(0, 0); STG(1, 1); STG(2, 2);
  VMW(4);  // A(0) landed (younger: A(1)2 + A(2)2 = 4)
  SBAR(); SCHED0();

  // TILE body: p = t&3; consume BC*, prefetch B(t+1) into BN*; stage A(t+3).
#define TILEX(p, t3, DO_STG, t1, DO_B, VMSTMT, BC0, BC1, BC2, BC3, BN0, BN1, BN2, BN3) { \
    bf16x8 a00 = LDA1(p, 0, 0), a01 = LDA1(p, 0, 1); \
    bf16x8 a10 = LDA1(p, 1, 0), a11 = LDA1(p, 1, 1); \
    bf16x8 a20 = LDA1(p, 2, 0), a21 = LDA1(p, 2, 1); \
    bf16x8 a30 = LDA1(p, 3, 0), a31 = LDA1(p, 3, 1); \
    if (DO_B) { BN0 = LB(pB0, 0, t1); BN1 = LB(pB0, 1, t1); \
                BN2 = LB(pB1, 0, t1); BN3 = LB(pB1, 1, t1); } \
    if (DO_STG) { STG((t3) & 3, t3); } \
    LGKM0(); VMSTMT; \
    SBAR(); SCHED0(); \
    __builtin_amdgcn_s_setprio(1); \
    acc[0][0] = MFMA(a00, BC0, acc[0][0], 0, 0, 0); \
    acc[1][0] = MFMA(a10, BC0, acc[1][0], 0, 0, 0); \
    acc[2][0] = MFMA(a20, BC0, acc[2][0], 0, 0, 0); \
    acc[3][0] = MFMA(a30, BC0, acc[3][0], 0, 0, 0); \
    acc[0][1] = MFMA(a00, BC2, acc[0][1], 0, 0, 0); \
    acc[1][1] = MFMA(a10, BC2, acc[1][1], 0, 0, 0); \
    acc[2][1] = MFMA(a20, BC2, acc[2][1], 0, 0, 0); \
    acc[3][1] = MFMA(a30, BC2, acc[3][1], 0, 0, 0); \
    acc[0][0] = MFMA(a01, BC1, acc[0][0], 0, 0, 0); \
    acc[1][0] = MFMA(a11, BC1, acc[1][0], 0, 0, 0); \
    acc[2][0] = MFMA(a21, BC1, acc[2][0], 0, 0, 0); \
    acc[3][0] = MFMA(a31, BC1, acc[3][0], 0, 0, 0); \
    acc[0][1] = MFMA(a01, BC3, acc[0][1], 0, 0, 0); \
    acc[1][1] = MFMA(a11, BC3, acc[1][1], 0, 0, 0); \
    acc[2][1] = MFMA(a21, BC3, acc[2][1], 0, 0, 0); \
    acc[3][1] = MFMA(a31, BC3, acc[3][1], 0, 0, 0); \
    __builtin_amdgcn_s_setprio(0); \
  }

  // 16 tiles; even t consume BX/load BY, odd t consume BY/load BX.
  // VMW targets A(t+1): younger-ops count (B(t)4 excluded when older).
  TILEX(0,  3, 1,  1, 1, VMW(8),  BX0, BX1, BX2, BX3, BY0, BY1, BY2, BY3);  // t=0
  TILEX(1,  4, 1,  2, 1, VMW(12), BY0, BY1, BY2, BY3, BX0, BX1, BX2, BX3);  // t=1
  TILEX(2,  5, 1,  3, 1, VMW(12), BX0, BX1, BX2, BX3, BY0, BY1, BY2, BY3);  // t=2
  TILEX(3,  6, 1,  4, 1, VMW(12), BY0, BY1, BY2, BY3, BX0, BX1, BX2, BX3);  // t=3
  TILEX(0,  7, 1,  5, 1, VMW(12), BX0, BX1, BX2, BX3, BY0, BY1, BY2, BY3);  // t=4
  TILEX(1,  8, 1,  6, 1, VMW(12), BY0, BY1, BY2, BY3, BX0, BX1, BX2, BX3);  // t=5
  TILEX(2,  9, 1,  7, 1, VMW(12), BX0, BX1, BX2, BX3, BY0, BY1, BY2, BY3);  // t=6
  TILEX(3, 10, 1,  8, 1, VMW(12), BY0, BY1, BY2, BY3, BX0, BX1, BX2, BX3);  // t=7
  TILEX(0, 11, 1,  9, 1, VMW(12), BX0, BX1, BX2, BX3, BY0, BY1, BY2, BY3);  // t=8
  TILEX(1, 12, 1, 10, 1, VMW(12), BY0, BY1, BY2, BY3, BX0, BX1, BX2, BX3);  // t=9
  TILEX(2, 13, 1, 11, 1, VMW(12), BX0, BX1, BX2, BX3, BY0, BY1, BY2, BY3);  // t=10
  TILEX(3, 14, 1, 12, 1, VMW(12), BY0, BY1, BY2, BY3, BX0, BX1, BX2, BX3);  // t=11
  TILEX(0, 15, 1, 13, 1, VMW(12), BX0, BX1, BX2, BX3, BY0, BY1, BY2, BY3);  // t=12
  TILEX(1,  0, 0, 14, 1, VMW(10), BY0, BY1, BY2, BY3, BX0, BX1, BX2, BX3);  // t=13
  TILEX(2,  0, 0, 15, 1, VMW(8),  BX0, BX1, BX2, BX3, BY0, BY1, BY2, BY3);  // t=14
  TILEX(3,  0, 0,  0, 0, (void)0, BY0, BY1, BY2, BY3, BX0, BX1, BX2, BX3);  // t=15
#undef TILEX
#undef STG
#undef LDA1
#undef LB

  // epilogue: o2 = sigmoid^2 bf16; leaf f32 out = clip(sigmoid)
#pragma unroll
  for (int i = 0; i < 4; ++i) {
    const int row0 = brow + (wr << 6) + i * 16 + ((lane >> 4) << 2);
#pragma unroll
    for (int j = 0; j < 2; ++j) {
      const int col = bcol + (wc << 5) + j * 16 + (lane & 15);
      const bool live = (col < UNITSN);
      float bz = live ? bias[col] : 0.f;
#pragma unroll
      for (int r = 0; r < 4; ++r) {
        float z = acc[i][j][r] + bz;
        float sg = fast_rcp(1.f + __expf(-z));
        float s2 = sg * sg;
        o2[(size_t)(row0 + r) * UNITSP + col] = f2bf(live ? s2 : 0.f);
        if (live) {
          outf[(size_t)(row0 + r) * CCLS + col] = fminf(fmaxf(sg, LEAF_LO), LEAF_HI);
        }
      }
    }
  }
}

// ---- GEMM2 (unchanged proven R5 kernel): 128x128 4-phase, EPI=sqrt(clip) ---
template <int NBX, int K>
__global__ __launch_bounds__(512, 4) void k_g128i(
    const unsigned short* __restrict__ A,
    const unsigned short* __restrict__ Bt,
    float* __restrict__ outf) {
  constexpr int NKT = K / 64;
  constexpr int BUFS = 32768;
  __shared__ char smem[2 * BUFS];

  const int nwg = (int)gridDim.x;
  const int qx = nwg >> 3;
  const int bid = (int)blockIdx.x;
  const int wg = (bid & 7) * qx + (bid >> 3);
  const int bx = wg % NBX, by = wg / NBX;
  const int brow = by << 7, bcol = bx << 7;

  const int tid = (int)threadIdx.x;
  const int lane = tid & 63;
  const int w = tid >> 6;
  const int wr = w >> 2, wc = w & 3;

  const unsigned short* gA =
      A + (size_t)(brow + (w << 3) + (lane >> 3)) * K + (((lane & 7) ^ (lane >> 3)) << 3);
  const unsigned short* gB =
      Bt + (size_t)(bcol + (w << 3) + (lane >> 3)) * K + (((lane & 7) ^ (lane >> 3)) << 3);
  const int sW = w << 10;

  const int s0 = (((lane >> 4) ^ (lane & 7)) << 4);
  const int aRB = (((wr << 6) + (lane & 15)) << 7);
  const int bRB = 16384 + (((wc << 5) + (lane & 15)) << 7);

#define STA2(b, u, gt) gload_lds16(gA + (size_t)((u) * 64) * K + (size_t)(gt) * 64, \
                                   smem + ((b) * BUFS + (u) * 8192) + sW)
#define STB2(b, u, gt) gload_lds16(gB + (size_t)((u) * 64) * K + (size_t)(gt) * 64, \
                                   smem + ((b) * BUFS + 16384 + (u) * 8192) + sW)
#define LDA2(b, i, ks) (*reinterpret_cast<const bf16x8*>( \
    smem + (b) * BUFS + aRB + (i) * 2048 + (s0 ^ ((ks) * 64))))
#define LDB2(b, j, ks) (*reinterpret_cast<const bf16x8*>( \
    smem + (b) * BUFS + bRB + (j) * 2048 + (s0 ^ ((ks) * 64))))

  f32x4 acc[4][2] = {};
  bf16x8 Bf0[2], Bf1[2];

  STB2(0, 0, 0); STB2(0, 1, 0);
  STA2(0, 0, 0); STA2(0, 1, 0);
  STB2(1, 0, 1); STB2(1, 1, 1);
  VMW(2);
  SBAR(); SCHED0();

  for (int it = 0; it < NKT / 2; ++it) {
    const int tb = 2 * it + 1, t2 = 2 * it + 2, t3 = 2 * it + 3;
    {
      bf16x8 a00 = LDA2(0, 0, 0), a01 = LDA2(0, 0, 1);
      bf16x8 a10 = LDA2(0, 1, 0), a11 = LDA2(0, 1, 1);
#pragma unroll
      for (int j = 0; j < 2; ++j) { Bf0[j] = LDB2(0, j, 0); Bf1[j] = LDB2(0, j, 1); }
      STA2(1, 0, tb); STA2(1, 1, tb);
      SBAR(); LGKM0(); SCHED0();
      __builtin_amdgcn_s_setprio(1);
#pragma unroll
      for (int j = 0; j < 2; ++j) { acc[0][j] = MFMA(a00, Bf0[j], acc[0][j], 0, 0, 0);
                                    acc[1][j] = MFMA(a10, Bf0[j], acc[1][j], 0, 0, 0); }
#pragma unroll
      for (int j = 0; j < 2; ++j) { acc[0][j] = MFMA(a01, Bf1[j], acc[0][j], 0, 0, 0);
                                    acc[1][j] = MFMA(a11, Bf1[j], acc[1][j], 0, 0, 0); }
      __builtin_amdgcn_s_setprio(0);
      SBAR(); SCHED0();
    }
    {
      bf16x8 a00 = LDA2(0, 2, 0), a01 = LDA2(0, 2, 1);
      bf16x8 a10 = LDA2(0, 3, 0), a11 = LDA2(0, 3, 1);
      if (t2 < NKT) { STB2(0, 0, t2); STB2(0, 1, t2); }
      SBAR(); LGKM0(); SCHED0();
      __builtin_amdgcn_s_setprio(1);
#pragma unroll
      for (int j = 0; j < 2; ++j) { acc[2][j] = MFMA(a00, Bf0[j], acc[2][j], 0, 0, 0);
                                    acc[3][j] = MFMA(a10, Bf0[j], acc[3][j], 0, 0, 0); }
#pragma unroll
      for (int j = 0; j < 2; ++j) { acc[2][j] = MFMA(a01, Bf1[j], acc[2][j], 0, 0, 0);
                                    acc[3][j] = MFMA(a11, Bf1[j], acc[3][j], 0, 0, 0); }
      __builtin_amdgcn_s_setprio(0);
      if (t2 < NKT) { VMW(2); } else { VMW(0); }
      SBAR(); SCHED0();
    }
    {
      bf16x8 a00 = LDA2(1, 0, 0), a01 = LDA2(1, 0, 1);
      bf16x8 a10 = LDA2(1, 1, 0), a11 = LDA2(1, 1, 1);
#pragma unroll
      for (int j = 0; j < 2; ++j) { Bf0[j] = LDB2(1, j, 0); Bf1[j] = LDB2(1, j, 1); }
      if (t2 < NKT) { STA2(0, 0, t2); STA2(0, 1, t2); }
      SBAR(); LGKM0(); SCHED0();
      __builtin_amdgcn_s_setprio(1);
#pragma unroll
      for (int j = 0; j < 2; ++j) { acc[0][j] = MFMA(a00, Bf0[j], acc[0][j], 0, 0, 0);
                                    acc[1][j] = MFMA(a10, Bf0[j], acc[1][j], 0, 0, 0); }
#pragma unroll
      for (int j = 0; j < 2; ++j) { acc[0][j] = MFMA(a01, Bf1[j], acc[0][j], 0, 0, 0);
                                    acc[1][j] = MFMA(a11, Bf1[j], acc[1][j], 0, 0, 0); }
      __builtin_amdgcn_s_setprio(0);
      SBAR(); SCHED0();
    }
    {
      bf16x8 a00 = LDA2(1, 2, 0), a01 = LDA2(1, 2, 1);
      bf16x8 a10 = LDA2(1, 3, 0), a11 = LDA2(1, 3, 1);
      if (t3 < NKT) { STB2(1, 0, t3); STB2(1, 1, t3); }
      SBAR(); LGKM0(); SCHED0();
      __builtin_amdgcn_s_setprio(1);
#pragma unroll
      for (int j = 0; j < 2; ++j) { acc[2][j] = MFMA(a00, Bf0[j], acc[2][j], 0, 0, 0);
                                    acc[3][j] = MFMA(a10, Bf0[j], acc[3][j], 0, 0, 0); }
#pragma unroll
      for (int j = 0; j < 2; ++j) { acc[2][j] = MFMA(a01, Bf1[j], acc[2][j], 0, 0, 0);
                                    acc[3][j] = MFMA(a11, Bf1[j], acc[3][j], 0, 0, 0); }
      __builtin_amdgcn_s_setprio(0);
      if (t3 < NKT) { VMW(2); }
      SBAR(); SCHED0();
    }
  }

#pragma unroll
  for (int i = 0; i < 4; ++i) {
    const int row0 = brow + (wr << 6) + i * 16 + ((lane >> 4) << 2);
#pragma unroll
    for (int j = 0; j < 2; ++j) {
      const int col = bcol + (wc << 5) + j * 16 + (lane & 15);
      if (col < NINT) {
#pragma unroll
        for (int r = 0; r < 4; ++r) {
          float s = acc[i][j][r];
          s = fminf(fmaxf(s, EPSV), 1.f - EPSV);
          outf[(size_t)(row0 + r) * CCLS + UNITSN + col] = fast_sqrt(s);
        }
      }
    }
  }
#undef STA2
#undef STB2
#undef LDA2
#undef LDB2
}

// ---- launch ----------------------------------------------------------------

extern "C" void kernel_launch(void* const* d_in, const int* in_sizes, int n_in,
                              void* d_out, int out_size, void* d_ws, size_t ws_size,
                              hipStream_t stream) {
  const float* inputs = (const float*)d_in[0];  // B x D
  const float* linear = (const float*)d_in[1];  // D x UNITS
  const float* bias   = (const float*)d_in[2];  // UNITS
  const float* R_t    = (const float*)d_in[3];  // C x UNITS
  float* out = (float*)d_out;                   // B x C

  char* ws = (char*)d_ws;
  unsigned short* Ab  = (unsigned short*)(ws);             // 16384x1024 bf16 = 32 MiB
  unsigned short* Wt  = (unsigned short*)(ws + 33554432);  // 1536x1024 bf16 = 3 MiB
  unsigned short* RbI = (unsigned short*)(ws + 36700160);  // 512x1536 bf16 = 1.5 MiB
  unsigned short* O2  = (unsigned short*)(ws + 38273024);  // 16384x1536 bf16 = 48 MiB

  // merged prep: A cvt + W^T + internal-R pack (one dispatch)
  k_prep<<<2048, 256, 0, stream>>>(inputs, linear, R_t, Ab, Wt, RbI);

  // GEMM1: B-in-regs kernel. grid = 128*12 = 1536, 2 blk/CU, 3 rounds
  k_gemm1b<<<1536, 512, 0, stream>>>(Ab, Wt, bias, O2, out);
  // GEMM2: internal classes (proven R5 kernel). M=16384, N=512, K=1536
  k_g128i<4, UNITSP><<<512, 512, 0, stream>>>(O2, RbI, out);
}

// Round 9
// 122.244 us; speedup vs baseline: 1.3178x; 1.3178x over previous
//
#include <hip/hip_runtime.h>
#include <stdint.h>

// Problem constants (HierarchicalAWX): B=16384, D=1024, UNITS=1500, C=2000
// Structural fact: R_t[0:1500] == eye(1500) => leaf outputs are elementwise
// clip(sigmoid, 1e-3, sqrt(1-1e-6)) from GEMM1's epilogue; only the 500
// internal classes need the second GEMM.
#define BROWS 16384
#define DDIM 1024
#define UNITSN 1500
#define UNITSP 1536   // padded K2 / N1
#define CCLS 2000
#define NINT 500      // internal classes
#define NINTP 512     // padded
#define EPSV 1e-6f
#define LEAF_LO 1e-3f        // sqrt(EPSV)
#define LEAF_HI 0.9999995f   // sqrt(1-EPSV)

typedef __bf16 bf16x8 __attribute__((ext_vector_type(8)));
typedef float f32x4 __attribute__((ext_vector_type(4)));
typedef unsigned short u16x4v __attribute__((ext_vector_type(4)));

__device__ __forceinline__ unsigned short f2bf(float f) {
  union { float f; uint32_t u; } x; x.f = f;
  uint32_t r = x.u + 0x7fffu + ((x.u >> 16) & 1u);
  return (unsigned short)(r >> 16);
}

__device__ __forceinline__ float fast_rcp(float x) {
  float r; asm("v_rcp_f32 %0, %1" : "=v"(r) : "v"(x)); return r;
}
__device__ __forceinline__ float fast_sqrt(float x) {
  float r; asm("v_sqrt_f32 %0, %1" : "=v"(r) : "v"(x)); return r;
}

// async global -> LDS, 16B per lane. LDS dest is wave-uniform base; HW adds lane*16.
__device__ __forceinline__ void gload_lds16(const void* g, void* l) {
  __builtin_amdgcn_global_load_lds(
      reinterpret_cast<const __attribute__((address_space(1))) void*>(
          reinterpret_cast<uintptr_t>(g)),
      reinterpret_cast<__attribute__((address_space(3))) void*>(
          (uint32_t)reinterpret_cast<uintptr_t>(l)),
      16, 0, 0);
}

#define VMW(n) asm volatile("s_waitcnt vmcnt(" #n ")" ::: "memory")
#define LGKM0() asm volatile("s_waitcnt lgkmcnt(0)" ::: "memory")
#define SBAR() __builtin_amdgcn_s_barrier()
#define SCHED0() __builtin_amdgcn_sched_barrier(0)
#define MFMA __builtin_amdgcn_mfma_f32_16x16x32_bf16

// ---- merged prep kernel -----------------------------------------------------
__global__ __launch_bounds__(256) void k_prep(
    const float* __restrict__ inputs, const float* __restrict__ lin,
    const float* __restrict__ R, unsigned short* __restrict__ Ab,
    unsigned short* __restrict__ wt, unsigned short* __restrict__ Rb) {
  const int b = blockIdx.x, t = threadIdx.x;

  // --- W^T: lin (D x UNITS f32) -> wt (UNITSP x D bf16), zero-pad rows
  if (b < 1536) {
    __shared__ float tle[32][33];
    const int nb = (b % 48) * 32;  // over UNITSP
    const int kb = (b / 48) * 32;  // over D
    const int tx = t & 31, ty = t >> 5;
#pragma unroll
    for (int s = 0; s < 32; s += 8) {
      int k = kb + ty + s, n = nb + tx;
      tle[ty + s][tx] = (n < UNITSN) ? lin[k * UNITSN + n] : 0.f;
    }
    __syncthreads();
#pragma unroll
    for (int s = 0; s < 32; s += 8) {
      int n = nb + ty + s, k = kb + tx;
      wt[n * DDIM + k] = f2bf(tle[tx][ty + s]);
    }
  }

  // --- A cvt: 16384x1024 f32 -> bf16
  const int gtid = b * 256 + t;
  const float4* in4 = (const float4*)inputs;
  for (int i = gtid; i < (BROWS * DDIM) / 4; i += 2048 * 256) {
    float4 v = in4[i];
    u16x4v o;
    o.x = f2bf(v.x); o.y = f2bf(v.y); o.z = f2bf(v.z); o.w = f2bf(v.w);
    *reinterpret_cast<u16x4v*>(Ab + i * 4) = o;
  }

  // --- internal R rows: Rb[r][u] = R[1500+r][u], (512 x 1536) zero-padded
  for (int i = gtid; i < NINTP * UNITSP; i += 2048 * 256) {
    int r = i / UNITSP;
    int u = i - r * UNITSP;
    float v = (r < NINT && u < UNITSN) ? R[(size_t)(UNITSN + r) * UNITSN + u] : 0.f;
    Rb[i] = f2bf(v);
  }
}

// ---- GEMM1 (m97/m103 verified template): 128x128 tile, 4 waves x 64x64 ----
// 256 threads, BK=64, SINGLE 32KB LDS buffer (A 16KB + B 16KB), plain
// __syncthreads() (compiler emits vmcnt/lgkm drains), 32 MFMA per barrier.
// VGPR capped via __launch_bounds__(256,3) -> 3 blocks/CU (12 waves/CU):
// co-resident blocks overlap the barrier drain AND the epilogue store burst
// (m114 mechanism). XOR-swizzle both sides (rule #21): staging source chunk
// pre-XORed by row&7; fragment reads XOR the same pattern -> 0 conflicts.
__global__ __launch_bounds__(256, 3) void k_gemm1c(
    const unsigned short* __restrict__ A,   // 16384 x 1024 bf16
    const unsigned short* __restrict__ Bt,  // 1536 x 1024 bf16 (W^T)
    const float* __restrict__ bias,
    unsigned short* __restrict__ o2,        // 16384 x 1536 bf16
    float* __restrict__ outf) {             // leaf cols of 16384 x 2000 f32
  constexpr int K = DDIM;     // 1024 -> 16 K-tiles of 64
  constexpr int NKT = K / 64;
  constexpr int NBX = 12;
  __shared__ char smem[32768];  // A[128][64] + B[128][64] bf16

  // T1: XCD-aware bijective swizzle (grid = 1536, % 8 == 0)
  const int nwg = (int)gridDim.x;
  const int qx = nwg >> 3;
  const int bid = (int)blockIdx.x;
  const int wg = (bid & 7) * qx + (bid >> 3);
  const int bx = wg % NBX, by = wg / NBX;
  const int brow = by << 7, bcol = bx << 7;

  const int tid = (int)threadIdx.x;
  const int lane = tid & 63;
  const int w = tid >> 6;          // 4 waves
  const int wr = w >> 1, wc = w & 1;  // 2x2, each 64x64

  // staging: thread covers row tid>>3 (0..31) + 32h, chunk tid&7 (16B).
  // Source chunk pre-XORed by row&7 so linear LDS write lands swizzled.
  const unsigned short* gA =
      A + (size_t)(brow + (tid >> 3)) * K + (((tid & 7) ^ ((tid >> 3) & 7)) << 3);
  const unsigned short* gB =
      Bt + (size_t)(bcol + (tid >> 3)) * K + (((tid & 7) ^ ((tid >> 3) & 7)) << 3);
  const int sW = w << 10;  // wave-uniform base within each 32-row call (4KB)

  // fragment reads: row = base + (lane&15); slot = ((lane>>4) ^ (lane&7)) ^ (ks*4)
  const int s0 = (((lane >> 4) ^ (lane & 7)) << 4);
  const int aOff = (((wr << 6) + (lane & 15)) << 7) + s0;
  const int bOff = 16384 + (((wc << 6) + (lane & 15)) << 7) + s0;

  // 8 gload_lds calls stage the full 128x64 A + 128x64 B tile (4KB each)
#define STG8(t) do { \
    gload_lds16(gA + (size_t)(t) * 64,                    smem + 0     + sW); \
    gload_lds16(gA + (size_t)32 * K + (size_t)(t) * 64,   smem + 4096  + sW); \
    gload_lds16(gA + (size_t)64 * K + (size_t)(t) * 64,   smem + 8192  + sW); \
    gload_lds16(gA + (size_t)96 * K + (size_t)(t) * 64,   smem + 12288 + sW); \
    gload_lds16(gB + (size_t)(t) * 64,                    smem + 16384 + sW); \
    gload_lds16(gB + (size_t)32 * K + (size_t)(t) * 64,   smem + 20480 + sW); \
    gload_lds16(gB + (size_t)64 * K + (size_t)(t) * 64,   smem + 24576 + sW); \
    gload_lds16(gB + (size_t)96 * K + (size_t)(t) * 64,   smem + 28672 + sW); \
  } while (0)
#define LDA1(i, ks) (*reinterpret_cast<const bf16x8*>(smem + (aOff ^ ((ks) * 64)) + (i) * 2048))
#define LDB1(j, ks) (*reinterpret_cast<const bf16x8*>(smem + (bOff ^ ((ks) * 64)) + (j) * 2048))

  f32x4 acc[4][4] = {};

  for (int t = 0; t < NKT; ++t) {
    STG8(t);
    __syncthreads();  // drains vmcnt (stage landed) + lgkm; all waves aligned
    bf16x8 a0[4], a1[4], b0[4], b1[4];
#pragma unroll
    for (int i = 0; i < 4; ++i) { a0[i] = LDA1(i, 0); a1[i] = LDA1(i, 1); }
#pragma unroll
    for (int j = 0; j < 4; ++j) { b0[j] = LDB1(j, 0); b1[j] = LDB1(j, 1); }
#pragma unroll
    for (int i = 0; i < 4; ++i)
#pragma unroll
      for (int j = 0; j < 4; ++j) {
        acc[i][j] = MFMA(a0[i], b0[j], acc[i][j], 0, 0, 0);
        acc[i][j] = MFMA(a1[i], b1[j], acc[i][j], 0, 0, 0);
      }
    __syncthreads();  // all reads done before next tile's stage overwrites
  }
#undef STG8
#undef LDA1
#undef LDB1

  // epilogue: o2 = sigmoid^2 bf16; leaf f32 out = clip(sigmoid)
#pragma unroll
  for (int i = 0; i < 4; ++i) {
    const int row0 = brow + (wr << 6) + i * 16 + ((lane >> 4) << 2);
#pragma unroll
    for (int j = 0; j < 4; ++j) {
      const int col = bcol + (wc << 6) + j * 16 + (lane & 15);
      const bool live = (col < UNITSN);
      float bz = live ? bias[col] : 0.f;
#pragma unroll
      for (int r = 0; r < 4; ++r) {
        float z = acc[i][j][r] + bz;
        float sg = fast_rcp(1.f + __expf(-z));
        float s2 = sg * sg;
        o2[(size_t)(row0 + r) * UNITSP + col] = f2bf(live ? s2 : 0.f);
        if (live) {
          outf[(size_t)(row0 + r) * CCLS + col] = fminf(fmaxf(sg, LEAF_LO), LEAF_HI);
        }
      }
    }
  }
}

// ---- GEMM2 (unchanged proven R5 kernel): 128x128 4-phase, EPI=sqrt(clip) ---
template <int NBX, int K>
__global__ __launch_bounds__(512, 4) void k_g128i(
    const unsigned short* __restrict__ A,
    const unsigned short* __restrict__ Bt,
    float* __restrict__ outf) {
  constexpr int NKT = K / 64;
  constexpr int BUFS = 32768;
  __shared__ char smem[2 * BUFS];

  const int nwg = (int)gridDim.x;
  const int qx = nwg >> 3;
  const int bid = (int)blockIdx.x;
  const int wg = (bid & 7) * qx + (bid >> 3);
  const int bx = wg % NBX, by = wg / NBX;
  const int brow = by << 7, bcol = bx << 7;

  const int tid = (int)threadIdx.x;
  const int lane = tid & 63;
  const int w = tid >> 6;
  const int wr = w >> 2, wc = w & 3;

  const unsigned short* gA =
      A + (size_t)(brow + (w << 3) + (lane >> 3)) * K + (((lane & 7) ^ (lane >> 3)) << 3);
  const unsigned short* gB =
      Bt + (size_t)(bcol + (w << 3) + (lane >> 3)) * K + (((lane & 7) ^ (lane >> 3)) << 3);
  const int sW = w << 10;

  const int s0 = (((lane >> 4) ^ (lane & 7)) << 4);
  const int aRB = (((wr << 6) + (lane & 15)) << 7);
  const int bRB = 16384 + (((wc << 5) + (lane & 15)) << 7);

#define STA2(b, u, gt) gload_lds16(gA + (size_t)((u) * 64) * K + (size_t)(gt) * 64, \
                                   smem + ((b) * BUFS + (u) * 8192) + sW)
#define STB2(b, u, gt) gload_lds16(gB + (size_t)((u) * 64) * K + (size_t)(gt) * 64, \
                                   smem + ((b) * BUFS + 16384 + (u) * 8192) + sW)
#define LDA2(b, i, ks) (*reinterpret_cast<const bf16x8*>( \
    smem + (b) * BUFS + aRB + (i) * 2048 + (s0 ^ ((ks) * 64))))
#define LDB2(b, j, ks) (*reinterpret_cast<const bf16x8*>( \
    smem + (b) * BUFS + bRB + (j) * 2048 + (s0 ^ ((ks) * 64))))

  f32x4 acc[4][2] = {};
  bf16x8 Bf0[2], Bf1[2];

  STB2(0, 0, 0); STB2(0, 1, 0);
  STA2(0, 0, 0); STA2(0, 1, 0);
  STB2(1, 0, 1); STB2(1, 1, 1);
  VMW(2);
  SBAR(); SCHED0();

  for (int it = 0; it < NKT / 2; ++it) {
    const int tb = 2 * it + 1, t2 = 2 * it + 2, t3 = 2 * it + 3;
    {
      bf16x8 a00 = LDA2(0, 0, 0), a01 = LDA2(0, 0, 1);
      bf16x8 a10 = LDA2(0, 1, 0), a11 = LDA2(0, 1, 1);
#pragma unroll
      for (int j = 0; j < 2; ++j) { Bf0[j] = LDB2(0, j, 0); Bf1[j] = LDB2(0, j, 1); }
      STA2(1, 0, tb); STA2(1, 1, tb);
      SBAR(); LGKM0(); SCHED0();
      __builtin_amdgcn_s_setprio(1);
#pragma unroll
      for (int j = 0; j < 2; ++j) { acc[0][j] = MFMA(a00, Bf0[j], acc[0][j], 0, 0, 0);
                                    acc[1][j] = MFMA(a10, Bf0[j], acc[1][j], 0, 0, 0); }
#pragma unroll
      for (int j = 0; j < 2; ++j) { acc[0][j] = MFMA(a01, Bf1[j], acc[0][j], 0, 0, 0);
                                    acc[1][j] = MFMA(a11, Bf1[j], acc[1][j], 0, 0, 0); }
      __builtin_amdgcn_s_setprio(0);
      SBAR(); SCHED0();
    }
    {
      bf16x8 a00 = LDA2(0, 2, 0), a01 = LDA2(0, 2, 1);
      bf16x8 a10 = LDA2(0, 3, 0), a11 = LDA2(0, 3, 1);
      if (t2 < NKT) { STB2(0, 0, t2); STB2(0, 1, t2); }
      SBAR(); LGKM0(); SCHED0();
      __builtin_amdgcn_s_setprio(1);
#pragma unroll
      for (int j = 0; j < 2; ++j) { acc[2][j] = MFMA(a00, Bf0[j], acc[2][j], 0, 0, 0);
                                    acc[3][j] = MFMA(a10, Bf0[j], acc[3][j], 0, 0, 0); }
#pragma unroll
      for (int j = 0; j < 2; ++j) { acc[2][j] = MFMA(a01, Bf1[j], acc[2][j], 0, 0, 0);
                                    acc[3][j] = MFMA(a11, Bf1[j], acc[3][j], 0, 0, 0); }
      __builtin_amdgcn_s_setprio(0);
      if (t2 < NKT) { VMW(2); } else { VMW(0); }
      SBAR(); SCHED0();
    }
    {
      bf16x8 a00 = LDA2(1, 0, 0), a01 = LDA2(1, 0, 1);
      bf16x8 a10 = LDA2(1, 1, 0), a11 = LDA2(1, 1, 1);
#pragma unroll
      for (int j = 0; j < 2; ++j) { Bf0[j] = LDB2(1, j, 0); Bf1[j] = LDB2(1, j, 1); }
      if (t2 < NKT) { STA2(0, 0, t2); STA2(0, 1, t2); }
      SBAR(); LGKM0(); SCHED0();
      __builtin_amdgcn_s_setprio(1);
#pragma unroll
      for (int j = 0; j < 2; ++j) { acc[0][j] = MFMA(a00, Bf0[j], acc[0][j], 0, 0, 0);
                                    acc[1][j] = MFMA(a10, Bf0[j], acc[1][j], 0, 0, 0); }
#pragma unroll
      for (int j = 0; j < 2; ++j) { acc[0][j] = MFMA(a01, Bf1[j], acc[0][j], 0, 0, 0);
                                    acc[1][j] = MFMA(a11, Bf1[j], acc[1][j], 0, 0, 0); }
      __builtin_amdgcn_s_setprio(0);
      SBAR(); SCHED0();
    }
    {
      bf16x8 a00 = LDA2(1, 2, 0), a01 = LDA2(1, 2, 1);
      bf16x8 a10 = LDA2(1, 3, 0), a11 = LDA2(1, 3, 1);
      if (t3 < NKT) { STB2(1, 0, t3); STB2(1, 1, t3); }
      SBAR(); LGKM0(); SCHED0();
      __builtin_amdgcn_s_setprio(1);
#pragma unroll
      for (int j = 0; j < 2; ++j) { acc[2][j] = MFMA(a00, Bf0[j], acc[2][j], 0, 0, 0);
                                    acc[3][j] = MFMA(a10, Bf0[j], acc[3][j], 0, 0, 0); }
#pragma unroll
      for (int j = 0; j < 2; ++j) { acc[2][j] = MFMA(a01, Bf1[j], acc[2][j], 0, 0, 0);
                                    acc[3][j] = MFMA(a11, Bf1[j], acc[3][j], 0, 0, 0); }
      __builtin_amdgcn_s_setprio(0);
      if (t3 < NKT) { VMW(2); }
      SBAR(); SCHED0();
    }
  }

#pragma unroll
  for (int i = 0; i < 4; ++i) {
    const int row0 = brow + (wr << 6) + i * 16 + ((lane >> 4) << 2);
#pragma unroll
    for (int j = 0; j < 2; ++j) {
      const int col = bcol + (wc << 5) + j * 16 + (lane & 15);
      if (col < NINT) {
#pragma unroll
        for (int r = 0; r < 4; ++r) {
          float s = acc[i][j][r];
          s = fminf(fmaxf(s, EPSV), 1.f - EPSV);
          outf[(size_t)(row0 + r) * CCLS + UNITSN + col] = fast_sqrt(s);
        }
      }
    }
  }
#undef STA2
#undef STB2
#undef LDA2
#undef LDB2
}

// ---- launch ----------------------------------------------------------------

extern "C" void kernel_launch(void* const* d_in, const int* in_sizes, int n_in,
                              void* d_out, int out_size, void* d_ws, size_t ws_size,
                              hipStream_t stream) {
  const float* inputs = (const float*)d_in[0];  // B x D
  const float* linear = (const float*)d_in[1];  // D x UNITS
  const float* bias   = (const float*)d_in[2];  // UNITS
  const float* R_t    = (const float*)d_in[3];  // C x UNITS
  float* out = (float*)d_out;                   // B x C

  char* ws = (char*)d_ws;
  unsigned short* Ab  = (unsigned short*)(ws);             // 16384x1024 bf16 = 32 MiB
  unsigned short* Wt  = (unsigned short*)(ws + 33554432);  // 1536x1024 bf16 = 3 MiB
  unsigned short* RbI = (unsigned short*)(ws + 36700160);  // 512x1536 bf16 = 1.5 MiB
  unsigned short* O2  = (unsigned short*)(ws + 38273024);  // 16384x1536 bf16 = 48 MiB

  // merged prep: A cvt + W^T + internal-R pack (one dispatch)
  k_prep<<<2048, 256, 0, stream>>>(inputs, linear, R_t, Ab, Wt, RbI);

  // GEMM1: m97-template 4-wave kernel. grid = 128*12 = 1536, 3 blk/CU, 2 rounds
  k_gemm1c<<<1536, 256, 0, stream>>>(Ab, Wt, bias, O2, out);
  // GEMM2: internal classes (proven R5 kernel). M=16384, N=512, K=1536
  k_g128i<4, UNITSP><<<512, 512, 0, stream>>>(O2, RbI, out);
}